// Round 9
// baseline (11381.820 us; speedup 1.0000x reference)
//
#include <hip/hip_runtime.h>
#include <math.h>

#define DEV_INLINE __device__ __forceinline__

constexpr int BB     = 32;
constexpr int DMODEL = 768;
constexpr int NHEAD  = 12;
constexpr int NPATCH = 196;
constexpr int NTOK   = 197;
constexpr int NLAYER = 12;
constexpr int NCLASS = 1000;
constexpr int MTOT   = BB * NTOK;   // 6304

typedef __attribute__((ext_vector_type(4))) float f32x4;
typedef __attribute__((ext_vector_type(8))) short bf16x8;

// fp32 -> (hi, lo) bf16 pair, both RNE. x ~= hi + lo with ~17 mantissa bits.
DEV_INLINE void split2(float x, unsigned short& hi, unsigned short& lo) {
    unsigned u = __builtin_bit_cast(unsigned, x);
    unsigned r = (u + 0x7FFFu + ((u >> 16) & 1u)) >> 16;
    hi = (unsigned short)r;
    float fh = __builtin_bit_cast(float, r << 16);
    float l = x - fh;
    unsigned ul = __builtin_bit_cast(unsigned, l);
    lo = (unsigned short)((ul + 0x7FFFu + ((ul >> 16) & 1u)) >> 16);
}

DEV_INLINE unsigned split_pack(float x) {
    unsigned short h, l; split2(x, h, l);
    return (unsigned)h | ((unsigned)l << 16);
}

// async 16B global -> LDS (wave-uniform LDS base + lane*16)
DEV_INLINE void gload16(const unsigned short* g, unsigned short* l) {
    __builtin_amdgcn_global_load_lds(
        (const __attribute__((address_space(1))) unsigned int*)g,
        (__attribute__((address_space(3))) unsigned int*)l, 16, 0, 0);
}

DEV_INLINE float block_reduce_sum(float v, float* sbuf) {
    #pragma unroll
    for (int off = 32; off > 0; off >>= 1) v += __shfl_down(v, off, 64);
    int lane = threadIdx.x & 63, w = threadIdx.x >> 6;
    __syncthreads();
    if (lane == 0) sbuf[w] = v;
    __syncthreads();
    return sbuf[0] + sbuf[1] + sbuf[2] + sbuf[3];
}

// ---------------------------------------------------------------- state init
__global__ void state_init(int* nTokPtr, int* prevValidPtr) {
    *nTokPtr = NTOK;
    *prevValidPtr = 0;
}

// ---------------------------------------------------------------- CLS row
__global__ __launch_bounds__(256)
void cls_init(const float* __restrict__ cls, const float* __restrict__ pos,
              float* __restrict__ tok) {
    int b = blockIdx.x;
    for (int i = threadIdx.x; i < DMODEL; i += 256)
        tok[(size_t)b * NTOK * DMODEL + i] = cls[i] + pos[i];
}

// ------------------------------------------------- patch weight convert (tiled)
__global__ __launch_bounds__(256)
void wconv_patch(const float* __restrict__ src, unsigned short* __restrict__ hi,
                 unsigned short* __restrict__ lo) {
    int id = blockIdx.x * 256 + threadIdx.x;   // (n, k-chunk8): 768*96
    if (id >= 768 * 96) return;
    int n = id / 96, ch = id % 96;
    int k = ch * 8;
    float4 a = *(const float4*)(src + (size_t)n * 768 + k);
    float4 b = *(const float4*)(src + (size_t)n * 768 + k + 4);
    unsigned short h[8], l[8];
    split2(a.x,h[0],l[0]); split2(a.y,h[1],l[1]); split2(a.z,h[2],l[2]); split2(a.w,h[3],l[3]);
    split2(b.x,h[4],l[4]); split2(b.y,h[5],l[5]); split2(b.z,h[6],l[6]); split2(b.w,h[7],l[7]);
    int npanel = n >> 7, c = n & 127;
    int kbi = k >> 5, chunk = (k >> 3) & 3;
    size_t base = ((size_t)npanel * 24 + kbi) * 4096
                + c * 32 + ((chunk ^ ((c >> 1) & 3)) << 3);
    bf16x8 hv, lv;
    #pragma unroll
    for (int j = 0; j < 8; ++j) { hv[j] = (short)h[j]; lv[j] = (short)l[j]; }
    *(bf16x8*)(hi + base) = hv;
    *(bf16x8*)(lo + base) = lv;
}

// ------------------------------------------------- per-layer weight convert
constexpr size_t WOFF_QKV  = 0;
constexpr size_t WOFF_PROJ = (size_t)768 * 2304;
constexpr size_t WOFF_FC1  = WOFF_PROJ + (size_t)768 * 768;
constexpr size_t WOFF_FC2  = WOFF_FC1 + (size_t)768 * 3072;
constexpr size_t WTOTAL    = WOFF_FC2 + (size_t)3072 * 768;   // 7,077,888

__global__ __launch_bounds__(256)
void wconv_layer(const float* __restrict__ qkvw, const float* __restrict__ projw,
                 const float* __restrict__ fc1w, const float* __restrict__ fc2w,
                 unsigned short* __restrict__ hi, unsigned short* __restrict__ lo) {
    __shared__ float tile[32][33];
    int bid = blockIdx.x;
    const float* src; int Kd, Nd; size_t dofs;
    if (bid < 1728)      { src = qkvw;  Kd = 768;  Nd = 2304; dofs = WOFF_QKV; }
    else if (bid < 2304) { bid -= 1728; src = projw; Kd = 768;  Nd = 768;  dofs = WOFF_PROJ; }
    else if (bid < 4608) { bid -= 2304; src = fc1w;  Kd = 768;  Nd = 3072; dofs = WOFF_FC1; }
    else                 { bid -= 4608; src = fc2w;  Kd = 3072; Nd = 768;  dofs = WOFF_FC2; }
    const int nkb = Kd >> 5;
    int ntx = Nd / 32;
    int n0 = (bid % ntx) * 32, k0 = (bid / ntx) * 32;
    int tx = threadIdx.x & 31, ty = threadIdx.x >> 5;   // 32 x 8
    #pragma unroll
    for (int i = 0; i < 32; i += 8)
        tile[ty + i][tx] = src[(size_t)(k0 + ty + i) * Nd + n0 + tx];   // [k][n]
    __syncthreads();
    int t = threadIdx.x;
    if (t < 128) {
        int nl = t >> 2, chunk = t & 3;
        unsigned short h[8], l[8];
        #pragma unroll
        for (int j = 0; j < 8; ++j) split2(tile[chunk * 8 + j][nl], h[j], l[j]);
        int n = n0 + nl, k = k0 + chunk * 8;
        int npanel = n >> 7, c = n & 127;
        int kbi = k >> 5;
        size_t base = dofs + ((size_t)npanel * nkb + kbi) * 4096
                    + c * 32 + ((chunk ^ ((c >> 1) & 3)) << 3);
        bf16x8 hv, lv;
        #pragma unroll
        for (int j = 0; j < 8; ++j) { hv[j] = (short)h[j]; lv[j] = (short)l[j]; }
        *(bf16x8*)(hi + base) = hv;
        *(bf16x8*)(lo + base) = lv;
    }
}

// ------------------------------------------------------------- MFMA GEMM (R9)
// 512 threads, 8 waves (4m x 2n), 128x128 tile. A fragments from global with
// REGISTER double-buffer prefetch (k+1 issued before MFMA k); B via gload_lds
// double-buffer (32KB LDS). m-major XCD chunks.
// ASRC: 0 = packed hi|lo<<16 uint activations [m][lda]; 1 = fp32 im2col of x
// EPI : 0 = +bias (packed C); 1 = +bias+resid (fp32 C); 2 = +bias,GELU (packed C);
//       3 = patch (+bias+pos, fp32 scatter into tok rows 1..196)
template<int ASRC, int EPI>
__global__ __launch_bounds__(512, 4)
void mfma_gemm(const void* __restrict__ A, int lda,
               const unsigned short* __restrict__ Wht,
               const unsigned short* __restrict__ Wlt,
               const float* __restrict__ bias,
               const float* __restrict__ resid,
               void* __restrict__ C, int ldc,
               int K, int Mtot, int gm, int gn,
               const int* __restrict__ nTokPtr) {
    const int nTok = (ASRC == 0) ? *nTokPtr : NTOK;
    int nb = gm * gn;
    int o = blockIdx.x;
    int qd = nb >> 3, r8 = nb & 7;
    int xcd = o & 7, wi = o >> 3;
    int fin = (xcd < r8 ? xcd * (qd + 1) : r8 * (qd + 1) + (xcd - r8) * qd) + wi;
    int bm = fin / gn, bn = fin - bm * gn;
    const int m0 = bm * 128, n0 = bn * 128;
    if (m0 >= Mtot) return;
    if (ASRC == 0) {
        int ts = m0 % NTOK;
        if (!(ts < nTok || ts + 128 > NTOK)) return;   // whole tile pruned
    }
    __shared__ unsigned short Bh[2][4096], Bl[2][4096];   // 32 KB total
    const int tid = threadIdx.x;
    const int lane = tid & 63, wid = tid >> 6;
    const int wm = wid >> 1, wn = wid & 1;
    const int fr = lane & 15, fg = lane >> 4;

    f32x4 acc[2][4];
    #pragma unroll
    for (int i = 0; i < 2; ++i)
        #pragma unroll
        for (int j = 0; j < 4; ++j) acc[i][j] = (f32x4){0.f, 0.f, 0.f, 0.f};

    // A row geometry: wave rows wm*32 + i*16 + fr
    int arow[2]; bool av[2]; size_t abase[2];
    #pragma unroll
    for (int i = 0; i < 2; ++i) {
        arow[i] = m0 + wm * 32 + i * 16 + fr;
        bool v = arow[i] < Mtot;
        if (ASRC == 0) v = v && (arow[i] % NTOK) < nTok;
        av[i] = v;
        if (ASRC == 0) abase[i] = (size_t)arow[i] * lda;
        else {
            int b = arow[i] / NPATCH, pp = arow[i] - b * NPATCH;
            int py = pp / 14, px = pp - py * 14;
            abase[i] = (size_t)b * (3 * 224 * 224) + (size_t)(py * 16) * 224 + px * 16;
        }
    }
    const int nkb = K >> 5;
    const int wbase = wid * 512;   // shorts: wave-uniform LDS base for gload
    const int g8 = tid * 8;

    auto issueB = [&](int kbi, int bufSel) {
        size_t tb = ((size_t)bn * nkb + kbi) * 4096 + g8;
        gload16(Wht + tb, &Bh[bufSel][wbase]);
        gload16(Wlt + tb, &Bl[bufSel][wbase]);
    };

    uint4  uA[2][2], uB2[2][2];
    float4 fA[2][2], fB2[2][2];

    auto loadA = [&](int kbi, uint4 (&u)[2][2], float4 (&f)[2][2]) {
        const int kb = kbi << 5;
        #pragma unroll
        for (int i = 0; i < 2; ++i) {
            if constexpr (ASRC == 0) {
                if (av[i]) {
                    const unsigned* ap = (const unsigned*)A + abase[i] + kb + fg * 8;
                    u[i][0] = *(const uint4*)ap;
                    u[i][1] = *(const uint4*)(ap + 4);
                } else { u[i][0] = u[i][1] = make_uint4(0, 0, 0, 0); }
            } else {
                if (av[i]) {
                    int k = kb + fg * 8;
                    size_t off = abase[i] + (size_t)(k >> 8) * (224 * 224)
                               + (size_t)((k >> 4) & 15) * 224 + (k & 15);
                    f[i][0] = *(const float4*)((const float*)A + off);
                    f[i][1] = *(const float4*)((const float*)A + off + 4);
                } else { f[i][0] = f[i][1] = make_float4(0.f, 0.f, 0.f, 0.f); }
            }
        }
    };

    auto compute = [&](int kbi, uint4 (&u)[2][2], float4 (&f)[2][2]) {
        const int cur = kbi & 1;
        bf16x8 ah[2], al2[2];
        #pragma unroll
        for (int i = 0; i < 2; ++i) {
            if constexpr (ASRC == 0) {
                const unsigned* uu = (const unsigned*)&u[i][0];
                #pragma unroll
                for (int e = 0; e < 8; ++e) {
                    ah[i][e]  = (short)(uu[e] & 0xffffu);
                    al2[i][e] = (short)(uu[e] >> 16);
                }
            } else {
                const float* ff = (const float*)&f[i][0];
                #pragma unroll
                for (int e = 0; e < 8; ++e) {
                    unsigned short h, l; split2(ff[e], h, l);
                    ah[i][e] = (short)h; al2[i][e] = (short)l;
                }
            }
        }
        bf16x8 bh4[4], bl4[4];
        #pragma unroll
        for (int j = 0; j < 4; ++j) {
            int col = wn * 64 + j * 16 + fr;
            int boff = col * 32 + ((fg ^ ((col >> 1) & 3)) << 3);
            bh4[j] = *(const bf16x8*)&Bh[cur][boff];
            bl4[j] = *(const bf16x8*)&Bl[cur][boff];
        }
        #pragma unroll
        for (int i = 0; i < 2; ++i)
            #pragma unroll
            for (int j = 0; j < 4; ++j) {
                acc[i][j] = __builtin_amdgcn_mfma_f32_16x16x32_bf16(ah[i],  bh4[j], acc[i][j], 0, 0, 0);
                acc[i][j] = __builtin_amdgcn_mfma_f32_16x16x32_bf16(ah[i],  bl4[j], acc[i][j], 0, 0, 0);
                acc[i][j] = __builtin_amdgcn_mfma_f32_16x16x32_bf16(al2[i], bh4[j], acc[i][j], 0, 0, 0);
            }
    };

    // prologue: B(0) + A(0) in flight
    issueB(0, 0);
    loadA(0, uA, fA);
    __syncthreads();   // B(0) resident (also waits A(0) — one-time cost)

    for (int kbi = 0; kbi < nkb; kbi += 2) {
        // even iter: compute buf0/regsA, prefetch (kbi+1) into buf1/regsB
        if (kbi + 1 < nkb) { issueB(kbi + 1, 1); loadA(kbi + 1, uB2, fB2); }
        compute(kbi, uA, fA);
        if (kbi + 1 >= nkb) break;
        __syncthreads();   // B(kbi+1) resident
        // odd iter: compute buf1/regsB, prefetch (kbi+2) into buf0/regsA
        if (kbi + 2 < nkb) { issueB(kbi + 2, 0); loadA(kbi + 2, uA, fA); }
        compute(kbi + 1, uB2, fB2);
        if (kbi + 2 < nkb) __syncthreads();   // B(kbi+2) resident
    }
    // ---- epilogue (C/D layout: col = lane&15, row = (lane>>4)*4 + e)
    #pragma unroll
    for (int i = 0; i < 2; ++i) {
        #pragma unroll
        for (int j = 0; j < 4; ++j) {
            #pragma unroll
            for (int e = 0; e < 4; ++e) {
                int m = m0 + wm * 32 + i * 16 + fg * 4 + e;
                int n = n0 + wn * 64 + j * 16 + fr;
                if (m >= Mtot) continue;
                if (ASRC == 0 && (m % NTOK) >= nTok) continue;
                float v = acc[i][j][e] + bias[n];
                if constexpr (EPI == 0) {
                    ((unsigned*)C)[(size_t)m * ldc + n] = split_pack(v);
                } else if constexpr (EPI == 1) {
                    ((float*)C)[(size_t)m * ldc + n] = v + resid[(size_t)m * ldc + n];
                } else if constexpr (EPI == 2) {
                    v = 0.5f * v * (1.0f + erff(v * 0.70710678118654752f));
                    ((unsigned*)C)[(size_t)m * ldc + n] = split_pack(v);
                } else {
                    int b = m / NPATCH, pp = m - b * NPATCH;
                    v += resid[(size_t)(1 + pp) * DMODEL + n];   // pos embed
                    ((float*)C)[((size_t)b * NTOK + 1 + pp) * DMODEL + n] = v;
                }
            }
        }
    }
}

// ---------------------------------------------------------------- LayerNorm
__global__ __launch_bounds__(256)
void ln_tok(const float* __restrict__ X, unsigned* __restrict__ Y,
            const float* __restrict__ w, const float* __restrict__ b,
            const int* __restrict__ nTokPtr) {
    int m = blockIdx.x;
    if ((m % NTOK) >= *nTokPtr) return;
    __shared__ float sbuf[4];
    const float* x = X + (size_t)m * DMODEL;
    int tid = threadIdx.x;
    float v[3];
    #pragma unroll
    for (int i = 0; i < 3; i++) v[i] = x[tid + i * 256];
    float mu = block_reduce_sum(v[0] + v[1] + v[2], sbuf) * (1.0f / 768.0f);
    float d2 = 0.f;
    #pragma unroll
    for (int i = 0; i < 3; i++) { float d = v[i] - mu; d2 = fmaf(d, d, d2); }
    float var = block_reduce_sum(d2, sbuf) * (1.0f / 768.0f);
    float rstd = rsqrtf(var + 1e-6f);
    #pragma unroll
    for (int i = 0; i < 3; i++) {
        int idx = tid + i * 256;
        float y = (v[i] - mu) * rstd * w[idx] + b[idx];
        Y[(size_t)m * DMODEL + idx] = split_pack(y);
    }
}

__global__ __launch_bounds__(256)
void ln_cls(const float* __restrict__ X, float* __restrict__ Y,
            const float* __restrict__ w, const float* __restrict__ b) {
    int bb = blockIdx.x;
    __shared__ float sbuf[4];
    const float* x = X + (size_t)bb * NTOK * DMODEL;
    int tid = threadIdx.x;
    float v[3];
    #pragma unroll
    for (int i = 0; i < 3; i++) v[i] = x[tid + i * 256];
    float mu = block_reduce_sum(v[0] + v[1] + v[2], sbuf) * (1.0f / 768.0f);
    float d2 = 0.f;
    #pragma unroll
    for (int i = 0; i < 3; i++) { float d = v[i] - mu; d2 = fmaf(d, d, d2); }
    float var = block_reduce_sum(d2, sbuf) * (1.0f / 768.0f);
    float rstd = rsqrtf(var + 1e-6f);
    #pragma unroll
    for (int i = 0; i < 3; i++) {
        int idx = tid + i * 256;
        Y[(size_t)bb * DMODEL + idx] = (v[i] - mu) * rstd * w[idx] + b[idx];
    }
}

// ---------------------------------------------------------------- attention v3
// split-bf16 MFMA flash attention. qkv is PACKED (hi|lo<<16). grid (b*h, 7).
__global__ __launch_bounds__(256)
void attn_v3(const unsigned* __restrict__ qkv, unsigned* __restrict__ outu,
             float* __restrict__ jacg, const int* __restrict__ nTokPtr) {
    const int nTok = *nTokPtr;
    const int bh = blockIdx.x;
    const int b = bh / NHEAD, h = bh % NHEAD;
    const int q0 = blockIdx.y * 32;
    if (q0 >= nTok) return;
    __shared__ unsigned short Kh[64 * 64], Kl[64 * 64];
    __shared__ unsigned short Vth[64 * 64], Vtl[64 * 64];
    __shared__ unsigned short Ph[32 * 64], Pl[32 * 64];
    __shared__ float Ss[32][68];
    __shared__ float mrow[32], lrow[32], frow[32];
    __shared__ float s0row[256], vnrow[256];
    __shared__ float vnpart[64][4];
    const int tid = threadIdx.x;
    const int lane = tid & 63, wv = tid >> 6;
    const int fr = lane & 15, fg = lane >> 4;
    const int qh = wv >> 1, xh = wv & 1;
    const unsigned* base = qkv + (size_t)b * NTOK * 2304 + (size_t)h * 64;

    {   // stage Q (packed) into Ss-as-uint
        unsigned* Qu = (unsigned*)&Ss[0][0];
        int r = tid >> 3, fc = tid & 7;
        int q = q0 + r;
        uint4 v = make_uint4(0,0,0,0), w = make_uint4(0,0,0,0);
        if (q < nTok) {
            v = *(const uint4*)(base + (size_t)q * 2304 + fc * 8);
            w = *(const uint4*)(base + (size_t)q * 2304 + fc * 8 + 4);
        }
        *(uint4*)&Qu[r * 68 + fc * 8] = v;
        *(uint4*)&Qu[r * 68 + fc * 8 + 4] = w;
    }
    if (tid < 32) { mrow[tid] = -INFINITY; lrow[tid] = 0.f; frow[tid] = 1.f; }
    __syncthreads();
    bf16x8 qah[2], qal[2];
    {   // extract Q fragments to regs
        const unsigned* Qu = (const unsigned*)&Ss[0][0];
        int r = qh * 16 + fr;
        #pragma unroll
        for (int s = 0; s < 2; ++s)
            #pragma unroll
            for (int i = 0; i < 8; ++i) {
                unsigned u = Qu[r * 68 + s * 32 + fg * 8 + i];
                qah[s][i] = (short)(u & 0xffffu);
                qal[s][i] = (short)(u >> 16);
            }
    }
    f32x4 oacc[2] = {{0,0,0,0},{0,0,0,0}};
    const int njt = (nTok + 63) >> 6;
    const int sj = tid & 63, sdh = tid >> 6;

    for (int jt = 0; jt < njt; ++jt) {
        const int jb = jt * 64;
        __syncthreads();
        {   // ---- stage K (swizzled rows) and V^T (scatter), both hi/lo bf16
            int j = jb + sj;
            uint4 ku[4], vu[4];
            if (j < nTok) {
                const unsigned* kr = base + (size_t)j * 2304 + 768 + sdh * 16;
                const unsigned* vr = base + (size_t)j * 2304 + 1536 + sdh * 16;
                ku[0] = *(const uint4*)kr;       ku[1] = *(const uint4*)(kr + 4);
                ku[2] = *(const uint4*)(kr + 8); ku[3] = *(const uint4*)(kr + 12);
                vu[0] = *(const uint4*)vr;       vu[1] = *(const uint4*)(vr + 4);
                vu[2] = *(const uint4*)(vr + 8); vu[3] = *(const uint4*)(vr + 12);
            } else {
                ku[0]=ku[1]=ku[2]=ku[3] = make_uint4(0,0,0,0);
                vu[0]=vu[1]=vu[2]=vu[3] = make_uint4(0,0,0,0);
            }
            const unsigned* kw = (const unsigned*)ku;
            bf16x8 kh0, kh1, kl0, kl1;
            #pragma unroll
            for (int i = 0; i < 8; ++i) {
                kh0[i] = (short)(kw[i] & 0xffffu);     kl0[i] = (short)(kw[i] >> 16);
                kh1[i] = (short)(kw[8 + i] & 0xffffu); kl1[i] = (short)(kw[8 + i] >> 16);
            }
            int c0 = sdh * 2;
            int ko0 = sj * 64 + ((c0 ^ (sj & 7)) << 3);
            int ko1 = sj * 64 + (((c0 + 1) ^ (sj & 7)) << 3);
            *(bf16x8*)&Kh[ko0] = kh0; *(bf16x8*)&Kh[ko1] = kh1;
            *(bf16x8*)&Kl[ko0] = kl0; *(bf16x8*)&Kl[ko1] = kl1;
            const unsigned* vw = (const unsigned*)vu;
            float pn = 0.f;
            #pragma unroll
            for (int i = 0; i < 16; ++i) {
                unsigned u = vw[i];
                int d = sdh * 16 + i;
                int si = d * 64 + (((sj >> 3) ^ (d & 7)) << 3) + (sj & 7);
                Vth[si] = (unsigned short)(u & 0xffffu);
                Vtl[si] = (unsigned short)(u >> 16);
                if (q0 == 0) {
                    float vf = __builtin_bit_cast(float, u << 16)
                             + __builtin_bit_cast(float, u & 0xffff0000u);
                    pn = fmaf(vf, vf, pn);
                }
            }
            if (q0 == 0) vnpart[sj][sdh] = pn;
        }
        __syncthreads();
        {   // ---- QK^T: wave (qh, xh) computes 16q x 32j
            f32x4 sacc[2] = {{0,0,0,0},{0,0,0,0}};
            #pragma unroll
            for (int s = 0; s < 2; ++s)
                #pragma unroll
                for (int t = 0; t < 2; ++t) {
                    int j = xh * 32 + t * 16 + fr;
                    int off = j * 64 + (((s * 4 + fg) ^ (j & 7)) << 3);
                    bf16x8 kbh = *(const bf16x8*)&Kh[off];
                    bf16x8 kbl = *(const bf16x8*)&Kl[off];
                    sacc[t] = __builtin_amdgcn_mfma_f32_16x16x32_bf16(qah[s], kbh, sacc[t], 0, 0, 0);
                    sacc[t] = __builtin_amdgcn_mfma_f32_16x16x32_bf16(qah[s], kbl, sacc[t], 0, 0, 0);
                    sacc[t] = __builtin_amdgcn_mfma_f32_16x16x32_bf16(qal[s], kbh, sacc[t], 0, 0, 0);
                }
            #pragma unroll
            for (int t = 0; t < 2; ++t)
                #pragma unroll
                for (int e = 0; e < 4; ++e) {
                    int q = q0 + qh * 16 + fg * 4 + e;
                    int j = jb + xh * 32 + t * 16 + fr;
                    Ss[qh * 16 + fg * 4 + e][xh * 32 + t * 16 + fr] =
                        (q < nTok && j < nTok) ? sacc[t][e] * 0.125f : -INFINITY;
                }
        }
        __syncthreads();
        {   // ---- wave-parallel online softmax (8 lanes/row)
            int q = tid >> 3, s = tid & 7;
            bool rowok = (q0 + q) < nTok;
            float4 va = *(const float4*)&Ss[q][s * 8];
            float4 vb = *(const float4*)&Ss[q][s * 8 + 4];
            if (q0 == 0 && q == 0) {
                *(float4*)&s0row[jb + s * 8] = va;
                *(float4*)&s0row[jb + s * 8 + 4] = vb;
            }
            float mx = fmaxf(fmaxf(fmaxf(va.x, va.y), fmaxf(va.z, va.w)),
                             fmaxf(fmaxf(vb.x, vb.y), fmaxf(vb.z, vb.w)));
            #pragma unroll
            for (int o = 1; o < 8; o <<= 1) mx = fmaxf(mx, __shfl_xor(mx, o));
            float mold = mrow[q];
            float mnew = fmaxf(mold, mx);
            float e[8];
            float sum = 0.f;
            if (rowok) {
                e[0] = expf(va.x - mnew); e[1] = expf(va.y - mnew);
                e[2] = expf(va.z - mnew); e[3] = expf(va.w - mnew);
                e[4] = expf(vb.x - mnew); e[5] = expf(vb.y - mnew);
                e[6] = expf(vb.z - mnew); e[7] = expf(vb.w - mnew);
                sum = ((e[0] + e[1]) + (e[2] + e[3])) + ((e[4] + e[5]) + (e[6] + e[7]));
            } else {
                #pragma unroll
                for (int i = 0; i < 8; ++i) e[i] = 0.f;
            }
            #pragma unroll
            for (int o = 1; o < 8; o <<= 1) sum += __shfl_xor(sum, o);
            bf16x8 ph, pl;   // truncation split (e >= 0)
            #pragma unroll
            for (int i = 0; i < 8; ++i) {
                unsigned u = __builtin_bit_cast(unsigned, e[i]);
                ph[i] = (short)(u >> 16);
                float r = e[i] - __builtin_bit_cast(float, u & 0xffff0000u);
                pl[i] = (short)(__builtin_bit_cast(unsigned, r) >> 16);
            }
            int poff = q * 64 + ((s ^ (q & 7)) << 3);
            *(bf16x8*)&Ph[poff] = ph;
            *(bf16x8*)&Pl[poff] = pl;
            if (s == 0 && rowok) {
                float f = expf(mold - mnew);
                lrow[q] = lrow[q] * f + sum;
                mrow[q] = mnew;
                frow[q] = f;
            }
            if (q0 == 0 && tid < 64) {
                int jj = jb + tid;
                if (jj < nTok)
                    vnrow[jj] = sqrtf(vnpart[tid][0] + vnpart[tid][1]
                                    + vnpart[tid][2] + vnpart[tid][3]);
            }
        }
        __syncthreads();
        {   // ---- PV: wave (qh, xh) computes 16q x 32d, accumulate
            float fe[4];
            #pragma unroll
            for (int e = 0; e < 4; ++e) fe[e] = frow[qh * 16 + fg * 4 + e];
            #pragma unroll
            for (int t = 0; t < 2; ++t)
                #pragma unroll
                for (int e = 0; e < 4; ++e) oacc[t][e] *= fe[e];
            #pragma unroll
            for (int s = 0; s < 2; ++s) {
                int pr = qh * 16 + fr;
                int poff = pr * 64 + (((s * 4 + fg) ^ (pr & 7)) << 3);
                bf16x8 pah = *(const bf16x8*)&Ph[poff];
                bf16x8 pal = *(const bf16x8*)&Pl[poff];
                #pragma unroll
                for (int t = 0; t < 2; ++t) {
                    int d = xh * 32 + t * 16 + fr;
                    int voff = d * 64 + (((s * 4 + fg) ^ (d & 7)) << 3);
                    bf16x8 vbh = *(const bf16x8*)&Vth[voff];
                    bf16x8 vbl = *(const bf16x8*)&Vtl[voff];
                    oacc[t] = __builtin_amdgcn_mfma_f32_16x16x32_bf16(pah, vbh, oacc[t], 0, 0, 0);
                    oacc[t] = __builtin_amdgcn_mfma_f32_16x16x32_bf16(pah, vbl, oacc[t], 0, 0, 0);
                    oacc[t] = __builtin_amdgcn_mfma_f32_16x16x32_bf16(pal, vbh, oacc[t], 0, 0, 0);
                }
            }
        }
    }
    // ---- epilogue: O = acc / l, packed store
    #pragma unroll
    for (int e = 0; e < 4; ++e) {
        int qr = qh * 16 + fg * 4 + e;
        int q = q0 + qr;
        if (q < nTok) {
            float inv = 1.0f / lrow[qr];
            #pragma unroll
            for (int t = 0; t < 2; ++t) {
                int n = h * 64 + xh * 32 + t * 16 + fr;
                outu[((size_t)b * NTOK + q) * DMODEL + n] = split_pack(oacc[t][e] * inv);
            }
        }
    }
    if (q0 == 0) {
        float m0f = mrow[0], l0 = lrow[0];
        for (int j = 1 + tid; j < nTok; j += 256)
            jacg[(size_t)bh * NPATCH + (j - 1)] = (expf(s0row[j] - m0f) / l0) * vnrow[j];
    }
}

// ------------------------------------------------------- prune decision
__global__ __launch_bounds__(256)
void decide_kernel(const float* __restrict__ jac,
                   int* __restrict__ nTokPtr, int* __restrict__ nTokNextPtr,
                   int* __restrict__ keepIdx, float* __restrict__ prevMassPtr,
                   int* __restrict__ prevValidPtr) {
    const int nTok = *nTokPtr;
    const int N = nTok - 1;
    const int tid = threadIdx.x;
    if (N <= 16) {
        if (tid == 0) { *prevValidPtr = 0; *nTokNextPtr = nTok; }
        for (int t = tid; t < nTok; t += 256) keepIdx[t] = t;
        return;
    }
    __shared__ float impF[NPATCH];
    __shared__ int   sel[NPATCH];
    __shared__ int   s_next;
    for (int j = tid; j < N; j += 256) {
        double s = 0.0;
        for (int r = 0; r < BB * NHEAD; r++) s += (double)jac[(size_t)r * NPATCH + j];
        impF[j] = (float)(s * (1.0 / 384.0));
    }
    __syncthreads();
    if (tid == 0) {
        double ms = 0.0;
        for (int j = 0; j < N; j++) ms += (double)impF[j];
        float massF = (float)ms;
        float meanF = (float)(ms / (double)N);
        double vs = 0.0;
        for (int j = 0; j < N; j++) { double d = (double)impF[j] - (double)meanF; vs += d * d; }
        float stdF = (float)sqrt(vs / (double)N);
        float rho = stdF / (meanF + 1e-6f);
        int nnext;
        if (*prevValidPtr != 0) {
            float pm = *prevMassPtr;
            float drift = fabsf(massF - pm) / (pm + 1e-6f);
            float kr = 1.0f - 0.01f * rho * (1.0f + drift);
            kr = fminf(fmaxf(kr, 0.0f), 1.0f);
            int t = (int)((double)N * (double)kr);
            nnext = t < 16 ? 16 : t;
        } else {
            nnext = N;
        }
        *prevMassPtr = massF;
        *prevValidPtr = 1;
        s_next = nnext;
        *nTokNextPtr = nnext + 1;
    }
    __syncthreads();
    int nnext = s_next;
    if (nnext < N) {
        for (int j = tid; j < N; j += 256) {
            float vj = impF[j];
            int rank = 0;
            for (int i = 0; i < N; i++) {
                float vi = impF[i];
                rank += (vi > vj || (vi == vj && i < j)) ? 1 : 0;
            }
            sel[j] = (rank < nnext) ? 1 : 0;
        }
        __syncthreads();
        if (tid == 0) {
            int c = 1;
            keepIdx[0] = 0;
            for (int j = 0; j < N; j++) if (sel[j]) keepIdx[c++] = j + 1;
        }
    } else {
        for (int t = tid; t < nTok; t += 256) keepIdx[t] = t;
    }
}

// ---------------------------------------------------------------- gather
__global__ __launch_bounds__(192)
void gather_kernel(const float* __restrict__ src, float* __restrict__ dst,
                   const int* __restrict__ keepIdx,
                   const int* __restrict__ nTokNextPtr, int* __restrict__ nTokPtr) {
    int nn = *nTokNextPtr;
    int m = blockIdx.x;
    int b = m / NTOK, t = m - b * NTOK;
    if (t < nn) {
        int s = keepIdx[t];
        const float4* sp = (const float4*)(src + ((size_t)b * NTOK + s) * DMODEL);
        float4* dp = (float4*)(dst + ((size_t)b * NTOK + t) * DMODEL);
        dp[threadIdx.x] = sp[threadIdx.x];
    }
    if (m == 0 && threadIdx.x == 0) *nTokPtr = nn;
}

// ---------------------------------------------------------------- head
__global__ __launch_bounds__(256)
void head_kernel(const float* __restrict__ lnC, const float* __restrict__ W,
                 const float* __restrict__ hb, float* __restrict__ out) {
    int b = blockIdx.x;
    int n = blockIdx.y * 256 + threadIdx.x;
    __shared__ float xs[DMODEL];
    for (int i = threadIdx.x; i < DMODEL; i += 256) xs[i] = lnC[(size_t)b * DMODEL + i];
    __syncthreads();
    if (n < NCLASS) {
        float acc = hb[n];
        for (int d = 0; d < DMODEL; d++) acc = fmaf(xs[d], W[(size_t)d * NCLASS + n], acc);
        out[(size_t)b * NCLASS + n] = acc;
    }
}

// ================================================================= launch
extern "C" void kernel_launch(void* const* d_in, const int* in_sizes, int n_in,
                              void* d_out, int out_size, void* d_ws, size_t ws_size,
                              hipStream_t stream) {
    const float* x       = (const float*)d_in[0];
    const float* patch_w = (const float*)d_in[1];
    const float* patch_b = (const float*)d_in[2];
    const float* cls_tok = (const float*)d_in[3];
    const float* pos     = (const float*)d_in[4];
    const float* ln1_w   = (const float*)d_in[5];
    const float* ln1_b   = (const float*)d_in[6];
    const float* qkv_w   = (const float*)d_in[7];
    const float* qkv_b   = (const float*)d_in[8];
    const float* proj_w  = (const float*)d_in[9];
    const float* proj_b  = (const float*)d_in[10];
    const float* ln2_w   = (const float*)d_in[11];
    const float* ln2_b   = (const float*)d_in[12];
    const float* fc1_w   = (const float*)d_in[13];
    const float* fc1_b   = (const float*)d_in[14];
    const float* fc2_w   = (const float*)d_in[15];
    const float* fc2_b   = (const float*)d_in[16];
    const float* norm_w  = (const float*)d_in[17];
    const float* norm_b  = (const float*)d_in[18];
    const float* head_w  = (const float*)d_in[19];
    const float* head_b  = (const float*)d_in[20];
    float* out = (float*)d_out;

    char* ws = (char*)d_ws;
    size_t off = 0;
    auto alloc = [&](size_t nbytes) {
        char* p = ws + off;
        off += ((nbytes + 255) / 256) * 256;
        return p;
    };
    float* tokA = (float*)alloc((size_t)MTOT * DMODEL * 4);
    float* tokB = (float*)alloc((size_t)MTOT * DMODEL * 4);
    char* uni = alloc((size_t)MTOT * 3072 * 4);   // qkvb (packed) | hbu (packed)
    unsigned* qkvb = (unsigned*)uni;
    unsigned* hbu = (unsigned*)uni;
    unsigned* xnu  = (unsigned*)alloc((size_t)MTOT * DMODEL * 4);
    unsigned* outu = (unsigned*)alloc((size_t)MTOT * DMODEL * 4);
    unsigned short* whi = (unsigned short*)alloc(WTOTAL * 2);
    unsigned short* wlo = (unsigned short*)alloc(WTOTAL * 2);
    unsigned short* wphi = (unsigned short*)alloc((size_t)768 * 768 * 2);
    unsigned short* wplo = (unsigned short*)alloc((size_t)768 * 768 * 2);
    float* jac  = (float*)alloc((size_t)BB * NHEAD * NPATCH * 4);
    float* lnC  = (float*)alloc((size_t)BB * DMODEL * 4);
    float* prevMass = (float*)alloc(32);
    int* ints = (int*)alloc(1024);
    int* nTokP = ints; int* nTokNextP = ints + 1; int* prevValidP = ints + 2;
    int* keepIdx = ints + 4;

    dim3 blk(256);
    dim3 blk512(512);
    state_init<<<dim3(1), dim3(1), 0, stream>>>(nTokP, prevValidP);
    wconv_patch<<<dim3(288), blk, 0, stream>>>(patch_w, wphi, wplo);
    cls_init<<<dim3(BB), blk, 0, stream>>>(cls_tok, pos, tokA);
    mfma_gemm<1, 3><<<dim3(49 * 6), blk512, 0, stream>>>(
        x, 0, wphi, wplo, patch_b, pos, tokA, DMODEL, 768, BB * NPATCH, 49, 6, nTokP);

    float* bufs[2] = {tokA, tokB};
    const int gm = (MTOT + 127) / 128;   // 50
    for (int l = 0; l < NLAYER; l++) {
        float* cur = bufs[l & 1];
        float* nxt = bufs[(l + 1) & 1];
        wconv_layer<<<dim3(6912), blk, 0, stream>>>(
            qkv_w + (size_t)l * 768 * 2304, proj_w + (size_t)l * 768 * 768,
            fc1_w + (size_t)l * 768 * 3072, fc2_w + (size_t)l * 3072 * 768, whi, wlo);
        ln_tok<<<dim3(MTOT), blk, 0, stream>>>(cur, xnu, ln1_w + l * 768, ln1_b + l * 768, nTokP);
        mfma_gemm<0, 0><<<dim3(gm * 18), blk512, 0, stream>>>(
            xnu, 768, whi + WOFF_QKV, wlo + WOFF_QKV, qkv_b + (size_t)l * 2304,
            nullptr, qkvb, 2304, 768, MTOT, gm, 18, nTokP);
        attn_v3<<<dim3(BB * NHEAD, 7), blk, 0, stream>>>(qkvb, outu, jac, nTokP);
        mfma_gemm<0, 1><<<dim3(gm * 6), blk512, 0, stream>>>(
            outu, 768, whi + WOFF_PROJ, wlo + WOFF_PROJ, proj_b + (size_t)l * 768,
            cur, cur, 768, 768, MTOT, gm, 6, nTokP);
        ln_tok<<<dim3(MTOT), blk, 0, stream>>>(cur, xnu, ln2_w + l * 768, ln2_b + l * 768, nTokP);
        mfma_gemm<0, 2><<<dim3(gm * 24), blk512, 0, stream>>>(
            xnu, 768, whi + WOFF_FC1, wlo + WOFF_FC1, fc1_b + (size_t)l * 3072,
            nullptr, hbu, 3072, 768, MTOT, gm, 24, nTokP);
        mfma_gemm<0, 1><<<dim3(gm * 6), blk512, 0, stream>>>(
            hbu, 3072, whi + WOFF_FC2, wlo + WOFF_FC2, fc2_b + (size_t)l * 768,
            cur, cur, 768, 3072, MTOT, gm, 6, nTokP);
        decide_kernel<<<dim3(1), blk, 0, stream>>>(jac, nTokP, nTokNextP, keepIdx,
                                                   prevMass, prevValidP);
        gather_kernel<<<dim3(MTOT), dim3(192), 0, stream>>>(cur, nxt, keepIdx, nTokNextP, nTokP);
    }
    ln_cls<<<dim3(BB), blk, 0, stream>>>(bufs[0], lnC, norm_w, norm_b);
    head_kernel<<<dim3(BB, 4), blk, 0, stream>>>(lnC, head_w, head_b, out);
}

// Round 10
// 5945.232 us; speedup vs baseline: 1.9144x; 1.9144x over previous
//
#include <hip/hip_runtime.h>
#include <math.h>

#define DEV_INLINE __device__ __forceinline__

constexpr int BB     = 32;
constexpr int DMODEL = 768;
constexpr int NHEAD  = 12;
constexpr int NPATCH = 196;
constexpr int NTOK   = 197;
constexpr int NLAYER = 12;
constexpr int NCLASS = 1000;
constexpr int MTOT   = BB * NTOK;   // 6304
constexpr int MPAD   = 6400;        // plane row padding (gm*128)

typedef __attribute__((ext_vector_type(4))) float f32x4;
typedef __attribute__((ext_vector_type(8))) short bf16x8;

// fp32 -> (hi, lo) bf16 pair, both RNE. x ~= hi + lo with ~17 mantissa bits.
DEV_INLINE void split2(float x, unsigned short& hi, unsigned short& lo) {
    unsigned u = __builtin_bit_cast(unsigned, x);
    unsigned r = (u + 0x7FFFu + ((u >> 16) & 1u)) >> 16;
    hi = (unsigned short)r;
    float fh = __builtin_bit_cast(float, r << 16);
    float l = x - fh;
    unsigned ul = __builtin_bit_cast(unsigned, l);
    lo = (unsigned short)((ul + 0x7FFFu + ((ul >> 16) & 1u)) >> 16);
}

DEV_INLINE float bf2f(unsigned short s) {
    return __builtin_bit_cast(float, ((unsigned)s) << 16);
}

// async 16B global -> LDS (wave-uniform LDS base + lane*16; global addr per-lane)
DEV_INLINE void gload16(const unsigned short* g, unsigned short* l) {
    __builtin_amdgcn_global_load_lds(
        (const __attribute__((address_space(1))) unsigned int*)g,
        (__attribute__((address_space(3))) unsigned int*)l, 16, 0, 0);
}

DEV_INLINE float block_reduce_sum(float v, float* sbuf) {
    #pragma unroll
    for (int off = 32; off > 0; off >>= 1) v += __shfl_down(v, off, 64);
    int lane = threadIdx.x & 63, w = threadIdx.x >> 6;
    __syncthreads();
    if (lane == 0) sbuf[w] = v;
    __syncthreads();
    return sbuf[0] + sbuf[1] + sbuf[2] + sbuf[3];
}

// ---------------------------------------------------------------- state init
__global__ void state_init(int* nTokPtr, int* prevValidPtr) {
    *nTokPtr = NTOK;
    *prevValidPtr = 0;
}

// ---------------------------------------------------------------- CLS row
__global__ __launch_bounds__(256)
void cls_init(const float* __restrict__ cls, const float* __restrict__ pos,
              float* __restrict__ tok) {
    int b = blockIdx.x;
    for (int i = threadIdx.x; i < DMODEL; i += 256)
        tok[(size_t)b * NTOK * DMODEL + i] = cls[i] + pos[i];
}

// ------------------------------------------------- patch weight convert (tiled)
__global__ __launch_bounds__(256)
void wconv_patch(const float* __restrict__ src, unsigned short* __restrict__ hi,
                 unsigned short* __restrict__ lo) {
    int id = blockIdx.x * 256 + threadIdx.x;   // (n, k-chunk8): 768*96
    if (id >= 768 * 96) return;
    int n = id / 96, ch = id % 96;
    int k = ch * 8;
    float4 a = *(const float4*)(src + (size_t)n * 768 + k);
    float4 b = *(const float4*)(src + (size_t)n * 768 + k + 4);
    unsigned short h[8], l[8];
    split2(a.x,h[0],l[0]); split2(a.y,h[1],l[1]); split2(a.z,h[2],l[2]); split2(a.w,h[3],l[3]);
    split2(b.x,h[4],l[4]); split2(b.y,h[5],l[5]); split2(b.z,h[6],l[6]); split2(b.w,h[7],l[7]);
    int npanel = n >> 7, c = n & 127;
    int kbi = k >> 5, chunk = (k >> 3) & 3;
    size_t base = ((size_t)npanel * 24 + kbi) * 4096
                + c * 32 + ((chunk ^ ((c >> 1) & 3)) << 3);
    bf16x8 hv, lv;
    #pragma unroll
    for (int j = 0; j < 8; ++j) { hv[j] = (short)h[j]; lv[j] = (short)l[j]; }
    *(bf16x8*)(hi + base) = hv;
    *(bf16x8*)(lo + base) = lv;
}

// ------------------------------------------------- per-layer weight convert
constexpr size_t WOFF_QKV  = 0;
constexpr size_t WOFF_PROJ = (size_t)768 * 2304;
constexpr size_t WOFF_FC1  = WOFF_PROJ + (size_t)768 * 768;
constexpr size_t WOFF_FC2  = WOFF_FC1 + (size_t)768 * 3072;
constexpr size_t WTOTAL    = WOFF_FC2 + (size_t)3072 * 768;   // 7,077,888

__global__ __launch_bounds__(256)
void wconv_layer(const float* __restrict__ qkvw, const float* __restrict__ projw,
                 const float* __restrict__ fc1w, const float* __restrict__ fc2w,
                 unsigned short* __restrict__ hi, unsigned short* __restrict__ lo) {
    __shared__ float tile[32][33];
    int bid = blockIdx.x;
    const float* src; int Kd, Nd; size_t dofs;
    if (bid < 1728)      { src = qkvw;  Kd = 768;  Nd = 2304; dofs = WOFF_QKV; }
    else if (bid < 2304) { bid -= 1728; src = projw; Kd = 768;  Nd = 768;  dofs = WOFF_PROJ; }
    else if (bid < 4608) { bid -= 2304; src = fc1w;  Kd = 768;  Nd = 3072; dofs = WOFF_FC1; }
    else                 { bid -= 4608; src = fc2w;  Kd = 3072; Nd = 768;  dofs = WOFF_FC2; }
    const int nkb = Kd >> 5;
    int ntx = Nd / 32;
    int n0 = (bid % ntx) * 32, k0 = (bid / ntx) * 32;
    int tx = threadIdx.x & 31, ty = threadIdx.x >> 5;   // 32 x 8
    #pragma unroll
    for (int i = 0; i < 32; i += 8)
        tile[ty + i][tx] = src[(size_t)(k0 + ty + i) * Nd + n0 + tx];   // [k][n]
    __syncthreads();
    int t = threadIdx.x;
    if (t < 128) {
        int nl = t >> 2, chunk = t & 3;
        unsigned short h[8], l[8];
        #pragma unroll
        for (int j = 0; j < 8; ++j) split2(tile[chunk * 8 + j][nl], h[j], l[j]);
        int n = n0 + nl, k = k0 + chunk * 8;
        int npanel = n >> 7, c = n & 127;
        int kbi = k >> 5;
        size_t base = dofs + ((size_t)npanel * nkb + kbi) * 4096
                    + c * 32 + ((chunk ^ ((c >> 1) & 3)) << 3);
        bf16x8 hv, lv;
        #pragma unroll
        for (int j = 0; j < 8; ++j) { hv[j] = (short)h[j]; lv[j] = (short)l[j]; }
        *(bf16x8*)(hi + base) = hv;
        *(bf16x8*)(lo + base) = lv;
    }
}

// ------------------------------------------------------------- MFMA GEMM (R10)
// R7 skeleton (256 thr, 128^2 tile, single-barrier dbuf, m-major XCD), but A
// comes from pre-swizzled hi/lo bf16 planes via global_load_lds (ASRC 0) —
// zero VALU staging. ASRC 1 (patch im2col) keeps the R7 reg-stage path.
// EPI: 0 = +bias -> PLAIN hi/lo planes (C,C2)
//      1 = +bias+resid -> fp32 C
//      2 = +bias,GELU -> SWIZZLED hi/lo planes (C,C2)
//      3 = patch +bias+pos -> fp32 scatter into tok rows 1..196
template<int ASRC, int EPI>
__global__ __launch_bounds__(256)
void mfma_gemm(const unsigned short* __restrict__ Ahp,
               const unsigned short* __restrict__ Alp,
               const float* __restrict__ Af,
               const unsigned short* __restrict__ Wht,
               const unsigned short* __restrict__ Wlt,
               const float* __restrict__ bias,
               const float* __restrict__ resid,
               void* __restrict__ C, void* __restrict__ C2,
               int ldc, int K, int Mtot, int gm, int gn,
               const int* __restrict__ nTokPtr) {
    const int nTok = (ASRC == 0) ? *nTokPtr : NTOK;
    // bijective XCD-chunk swizzle, m-major / n-inner (R7-proven locality)
    int nb = gm * gn;
    int o = blockIdx.x;
    int qd = nb >> 3, r8 = nb & 7;
    int xcd = o & 7, wi = o >> 3;
    int fin = (xcd < r8 ? xcd * (qd + 1) : r8 * (qd + 1) + (xcd - r8) * qd) + wi;
    int bm = fin / gn, bn = fin - bm * gn;
    const int m0 = bm * 128, n0 = bn * 128;
    if (m0 >= Mtot) return;
    if (ASRC == 0) {
        int ts = m0 % NTOK;
        if (!(ts < nTok || ts + 128 > NTOK)) return;   // whole tile pruned
    }
    __shared__ unsigned short Ah[2][4096], Al[2][4096];
    __shared__ unsigned short Bh[2][4096], Bl[2][4096];
    const int tid = threadIdx.x;
    const int lane = tid & 63, wid = tid >> 6;
    const int wm = wid >> 1, wn = wid & 1;
    const int fr = lane & 15, fg = lane >> 4;

    f32x4 acc[4][4];
    #pragma unroll
    for (int i = 0; i < 4; ++i)
        #pragma unroll
        for (int j = 0; j < 4; ++j) acc[i][j] = (f32x4){0.f, 0.f, 0.f, 0.f};

    const int nkb = K >> 5;
    const int wbase = wid * 512;
    const int g8 = tid * 8;

    // ASRC0: A plane gload geometry (planes pre-swizzled in global; linear copy)
    size_t arow_g = 0;
    if constexpr (ASRC == 0)
        arow_g = (size_t)(m0 + (tid >> 2)) * K + (tid & 3) * 8;

    // ASRC1: reg-stage geometry (R7 path)
    int arow = 0, acp = 0, aoff0 = 0, aoff1 = 0;
    bool aval = false; size_t abase = 0;
    if constexpr (ASRC == 1) {
        arow = tid >> 1;
        acp  = (tid & 1) * 2;
        int am = m0 + arow;
        aval = am < Mtot;
        int b = am / NPATCH, pp = am - b * NPATCH;
        int py = pp / 14, px = pp - py * 14;
        abase = (size_t)b * (3 * 224 * 224) + (size_t)(py * 16) * 224 + px * 16;
        int axor = (arow >> 1) & 3;
        aoff0 = arow * 32 + ((acp ^ axor) << 3);
        aoff1 = arow * 32 + (((acp + 1) ^ axor) << 3);
    }

    float4 freg[4];
    auto issueA = [&](int kbi, int bufSel) {
        if constexpr (ASRC == 0) {
            size_t ab = arow_g + (size_t)(kbi << 5);
            gload16(Ahp + ab,                  &Ah[bufSel][wbase]);
            gload16(Ahp + ab + (size_t)64 * K, &Ah[bufSel][wbase + 2048]);
            gload16(Alp + ab,                  &Al[bufSel][wbase]);
            gload16(Alp + ab + (size_t)64 * K, &Al[bufSel][wbase + 2048]);
        } else {
            if (aval) {
                int k = (kbi << 5) + acp * 8;
                size_t off = abase + (size_t)(k >> 8) * (224 * 224)
                           + (size_t)((k >> 4) & 15) * 224;
                freg[0] = *(const float4*)(Af + off);
                freg[1] = *(const float4*)(Af + off + 4);
                freg[2] = *(const float4*)(Af + off + 8);
                freg[3] = *(const float4*)(Af + off + 12);
            } else {
                freg[0] = freg[1] = freg[2] = freg[3] = make_float4(0.f, 0.f, 0.f, 0.f);
            }
        }
    };
    auto storeA = [&](int bufSel) {   // ASRC1 only
        unsigned ph[8], pl[8];
        const float* f = (const float*)&freg[0];
        #pragma unroll
        for (int j = 0; j < 8; ++j) {
            unsigned short h0, l0, h1, l1;
            split2(f[2 * j], h0, l0); split2(f[2 * j + 1], h1, l1);
            ph[j] = (unsigned)h0 | ((unsigned)h1 << 16);
            pl[j] = (unsigned)l0 | ((unsigned)l1 << 16);
        }
        *(uint4*)&Ah[bufSel][aoff0] = *(uint4*)&ph[0];
        *(uint4*)&Ah[bufSel][aoff1] = *(uint4*)&ph[4];
        *(uint4*)&Al[bufSel][aoff0] = *(uint4*)&pl[0];
        *(uint4*)&Al[bufSel][aoff1] = *(uint4*)&pl[4];
    };
    auto issueB = [&](int kbi, int bufSel) {
        size_t tb = ((size_t)bn * nkb + kbi) * 4096 + g8;
        gload16(Wht + tb,        &Bh[bufSel][wbase]);
        gload16(Wht + tb + 2048, &Bh[bufSel][wbase + 2048]);
        gload16(Wlt + tb,        &Bl[bufSel][wbase]);
        gload16(Wlt + tb + 2048, &Bl[bufSel][wbase + 2048]);
    };

    // prologue
    issueB(0, 0);
    issueA(0, 0);
    if constexpr (ASRC == 1) storeA(0);
    __syncthreads();

    for (int kbi = 0; kbi < nkb; ++kbi) {
        const int cur = kbi & 1;
        bf16x8 ah[4], al4[4], bh4[4], bl4[4];
        #pragma unroll
        for (int i = 0; i < 4; ++i) {
            int row = wm * 64 + i * 16 + fr;
            int aoff = row * 32 + ((fg ^ ((row >> 1) & 3)) << 3);
            ah[i]  = *(const bf16x8*)&Ah[cur][aoff];
            al4[i] = *(const bf16x8*)&Al[cur][aoff];
            int col = wn * 64 + i * 16 + fr;
            int boff = col * 32 + ((fg ^ ((col >> 1) & 3)) << 3);
            bh4[i] = *(const bf16x8*)&Bh[cur][boff];
            bl4[i] = *(const bf16x8*)&Bl[cur][boff];
        }
        if (kbi + 1 < nkb) {
            issueB(kbi + 1, cur ^ 1);
            issueA(kbi + 1, cur ^ 1);
        }
        __builtin_amdgcn_sched_barrier(0);
        #pragma unroll
        for (int i = 0; i < 4; ++i)
            #pragma unroll
            for (int j = 0; j < 4; ++j) {
                acc[i][j] = __builtin_amdgcn_mfma_f32_16x16x32_bf16(ah[i],  bh4[j], acc[i][j], 0, 0, 0);
                acc[i][j] = __builtin_amdgcn_mfma_f32_16x16x32_bf16(ah[i],  bl4[j], acc[i][j], 0, 0, 0);
                acc[i][j] = __builtin_amdgcn_mfma_f32_16x16x32_bf16(al4[i], bh4[j], acc[i][j], 0, 0, 0);
            }
        __builtin_amdgcn_sched_barrier(0);
        if (kbi + 1 < nkb) {
            if constexpr (ASRC == 1) storeA(cur ^ 1);
            __syncthreads();
        }
    }
    // ---- epilogue (C/D layout: col = lane&15, row = (lane>>4)*4 + e)
    #pragma unroll
    for (int i = 0; i < 4; ++i) {
        #pragma unroll
        for (int j = 0; j < 4; ++j) {
            #pragma unroll
            for (int e = 0; e < 4; ++e) {
                int m = m0 + wm * 64 + i * 16 + fg * 4 + e;
                int n = n0 + wn * 64 + j * 16 + fr;
                if (m >= Mtot) continue;
                if (ASRC == 0 && (m % NTOK) >= nTok) continue;
                float v = acc[i][j][e] + bias[n];
                if constexpr (EPI == 0 || EPI == 2) {
                    if constexpr (EPI == 2)
                        v = 0.5f * v * (1.0f + erff(v * 0.70710678118654752f));
                    unsigned short h, l; split2(v, h, l);
                    size_t dst;
                    if constexpr (EPI == 0)
                        dst = (size_t)m * ldc + n;
                    else
                        dst = (size_t)m * ldc + (n & ~31)
                            + ((((n >> 3) & 3) ^ ((m >> 1) & 3)) << 3) + (n & 7);
                    ((unsigned short*)C)[dst]  = h;
                    ((unsigned short*)C2)[dst] = l;
                } else if constexpr (EPI == 1) {
                    ((float*)C)[(size_t)m * ldc + n] = v + resid[(size_t)m * ldc + n];
                } else {
                    int b = m / NPATCH, pp = m - b * NPATCH;
                    v += resid[(size_t)(1 + pp) * DMODEL + n];   // pos embed
                    ((float*)C)[((size_t)b * NTOK + 1 + pp) * DMODEL + n] = v;
                }
            }
        }
    }
}

// ---------------------------------------------------------------- LayerNorm
// writes swizzled hi/lo A-planes (GEMM A format)
__global__ __launch_bounds__(256)
void ln_tok(const float* __restrict__ X, unsigned short* __restrict__ Yh,
            unsigned short* __restrict__ Yl,
            const float* __restrict__ w, const float* __restrict__ b,
            const int* __restrict__ nTokPtr) {
    int m = blockIdx.x;
    if ((m % NTOK) >= *nTokPtr) return;
    __shared__ float sbuf[4];
    __shared__ float yb[768];
    const float* x = X + (size_t)m * DMODEL;
    int tid = threadIdx.x;
    float v[3];
    #pragma unroll
    for (int i = 0; i < 3; i++) v[i] = x[tid + i * 256];
    float mu = block_reduce_sum(v[0] + v[1] + v[2], sbuf) * (1.0f / 768.0f);
    float d2 = 0.f;
    #pragma unroll
    for (int i = 0; i < 3; i++) { float d = v[i] - mu; d2 = fmaf(d, d, d2); }
    float var = block_reduce_sum(d2, sbuf) * (1.0f / 768.0f);
    float rstd = rsqrtf(var + 1e-6f);
    #pragma unroll
    for (int i = 0; i < 3; i++) {
        int idx = tid + i * 256;
        yb[idx] = (v[i] - mu) * rstd * w[idx] + b[idx];
    }
    __syncthreads();
    if (tid < 96) {
        bf16x8 hv, lv;
        #pragma unroll
        for (int j = 0; j < 8; ++j) {
            unsigned short h, l; split2(yb[tid * 8 + j], h, l);
            hv[j] = (short)h; lv[j] = (short)l;
        }
        size_t dst = (size_t)m * 768 + (tid >> 2) * 32
                   + (((tid & 3) ^ ((m >> 1) & 3)) << 3);
        *(bf16x8*)(Yh + dst) = hv;
        *(bf16x8*)(Yl + dst) = lv;
    }
}

__global__ __launch_bounds__(256)
void ln_cls(const float* __restrict__ X, float* __restrict__ Y,
            const float* __restrict__ w, const float* __restrict__ b) {
    int bb = blockIdx.x;
    __shared__ float sbuf[4];
    const float* x = X + (size_t)bb * NTOK * DMODEL;
    int tid = threadIdx.x;
    float v[3];
    #pragma unroll
    for (int i = 0; i < 3; i++) v[i] = x[tid + i * 256];
    float mu = block_reduce_sum(v[0] + v[1] + v[2], sbuf) * (1.0f / 768.0f);
    float d2 = 0.f;
    #pragma unroll
    for (int i = 0; i < 3; i++) { float d = v[i] - mu; d2 = fmaf(d, d, d2); }
    float var = block_reduce_sum(d2, sbuf) * (1.0f / 768.0f);
    float rstd = rsqrtf(var + 1e-6f);
    #pragma unroll
    for (int i = 0; i < 3; i++) {
        int idx = tid + i * 256;
        Y[(size_t)bb * DMODEL + idx] = (v[i] - mu) * rstd * w[idx] + b[idx];
    }
}

// ---------------------------------------------------------------- attention
// split-bf16 MFMA flash attention. qkv = separate hi/lo planes [m][2304].
// grid (b*h, 7 q-tiles of 32). Output -> swizzled hi/lo planes (proj A).
// (R5-proven code.)
__global__ __launch_bounds__(256)
void attn_v4(const unsigned short* __restrict__ qh_g,
             const unsigned short* __restrict__ ql_g,
             unsigned short* __restrict__ oh_g,
             unsigned short* __restrict__ ol_g,
             float* __restrict__ jacg, const int* __restrict__ nTokPtr) {
    const int nTok = *nTokPtr;
    const int bh = blockIdx.x;
    const int b = bh / NHEAD, h = bh % NHEAD;
    const int q0 = blockIdx.y * 32;
    if (q0 >= nTok) return;
    __shared__ unsigned short Kh[64 * 64], Kl[64 * 64];
    __shared__ unsigned short Vth[64 * 64], Vtl[64 * 64];
    __shared__ unsigned short Ph[32 * 64], Pl[32 * 64];
    __shared__ float Ss[32][68];
    __shared__ float mrow[32], lrow[32], frow[32];
    __shared__ float s0row[256], vnrow[256];
    __shared__ float vnpart[64][4];
    const int tid = threadIdx.x;
    const int lane = tid & 63, wv = tid >> 6;
    const int fr = lane & 15, fg = lane >> 4;
    const int qh = wv >> 1, xh = wv & 1;

    bf16x8 qah[2], qal[2];
    {
        int q = q0 + qh * 16 + fr;
        int qe = q < nTok ? q : nTok - 1;
        const unsigned short* qrh = qh_g + (size_t)(b * NTOK + qe) * 2304 + h * 64;
        const unsigned short* qrl = ql_g + (size_t)(b * NTOK + qe) * 2304 + h * 64;
        #pragma unroll
        for (int s = 0; s < 2; ++s) {
            qah[s] = *(const bf16x8*)(qrh + s * 32 + fg * 8);
            qal[s] = *(const bf16x8*)(qrl + s * 32 + fg * 8);
        }
    }
    if (tid < 32) { mrow[tid] = -INFINITY; lrow[tid] = 0.f; frow[tid] = 1.f; }
    f32x4 oacc[2] = {{0,0,0,0},{0,0,0,0}};
    const int njt = (nTok + 63) >> 6;
    const int sj = tid & 63, sdh = tid >> 6;

    for (int jt = 0; jt < njt; ++jt) {
        const int jb = jt * 64;
        __syncthreads();
        {   // stage K (swizzled rows) and V^T (scatter), hi/lo bf16
            int j = jb + sj;
            bf16x8 kh0, kh1, kl0, kl1, vh0, vh1, vl0, vl1;
            if (j < nTok) {
                size_t rp = (size_t)(b * NTOK + j) * 2304 + h * 64;
                kh0 = *(const bf16x8*)(qh_g + rp + 768 + sdh * 16);
                kh1 = *(const bf16x8*)(qh_g + rp + 768 + sdh * 16 + 8);
                kl0 = *(const bf16x8*)(ql_g + rp + 768 + sdh * 16);
                kl1 = *(const bf16x8*)(ql_g + rp + 768 + sdh * 16 + 8);
                vh0 = *(const bf16x8*)(qh_g + rp + 1536 + sdh * 16);
                vh1 = *(const bf16x8*)(qh_g + rp + 1536 + sdh * 16 + 8);
                vl0 = *(const bf16x8*)(ql_g + rp + 1536 + sdh * 16);
                vl1 = *(const bf16x8*)(ql_g + rp + 1536 + sdh * 16 + 8);
            } else {
                bf16x8 z = {0,0,0,0,0,0,0,0};
                kh0=kh1=kl0=kl1=vh0=vh1=vl0=vl1 = z;
            }
            int c0 = sdh * 2;
            int ko0 = sj * 64 + ((c0 ^ (sj & 7)) << 3);
            int ko1 = sj * 64 + (((c0 + 1) ^ (sj & 7)) << 3);
            *(bf16x8*)&Kh[ko0] = kh0; *(bf16x8*)&Kh[ko1] = kh1;
            *(bf16x8*)&Kl[ko0] = kl0; *(bf16x8*)&Kl[ko1] = kl1;
            float pn = 0.f;
            #pragma unroll
            for (int i = 0; i < 16; ++i) {
                unsigned short vh = (unsigned short)(i < 8 ? vh0[i] : vh1[i - 8]);
                unsigned short vl = (unsigned short)(i < 8 ? vl0[i] : vl1[i - 8]);
                int d = sdh * 16 + i;
                int si = d * 64 + (((sj >> 3) ^ (d & 7)) << 3) + (sj & 7);
                Vth[si] = vh; Vtl[si] = vl;
                if (q0 == 0) {
                    float vf = bf2f(vh) + bf2f(vl);
                    pn = fmaf(vf, vf, pn);
                }
            }
            if (q0 == 0) vnpart[sj][sdh] = pn;
        }
        __syncthreads();
        {   // QK^T: wave (qh, xh) computes 16q x 32j
            f32x4 sacc[2] = {{0,0,0,0},{0,0,0,0}};
            #pragma unroll
            for (int s = 0; s < 2; ++s)
                #pragma unroll
                for (int t = 0; t < 2; ++t) {
                    int j = xh * 32 + t * 16 + fr;
                    int off = j * 64 + (((s * 4 + fg) ^ (j & 7)) << 3);
                    bf16x8 kbh = *(const bf16x8*)&Kh[off];
                    bf16x8 kbl = *(const bf16x8*)&Kl[off];
                    sacc[t] = __builtin_amdgcn_mfma_f32_16x16x32_bf16(qah[s], kbh, sacc[t], 0, 0, 0);
                    sacc[t] = __builtin_amdgcn_mfma_f32_16x16x32_bf16(qah[s], kbl, sacc[t], 0, 0, 0);
                    sacc[t] = __builtin_amdgcn_mfma_f32_16x16x32_bf16(qal[s], kbh, sacc[t], 0, 0, 0);
                }
            #pragma unroll
            for (int t = 0; t < 2; ++t)
                #pragma unroll
                for (int e = 0; e < 4; ++e) {
                    int q = q0 + qh * 16 + fg * 4 + e;
                    int j = jb + xh * 32 + t * 16 + fr;
                    Ss[qh * 16 + fg * 4 + e][xh * 32 + t * 16 + fr] =
                        (q < nTok && j < nTok) ? sacc[t][e] * 0.125f : -INFINITY;
                }
        }
        __syncthreads();
        {   // wave-parallel online softmax (8 lanes/row)
            int q = tid >> 3, s = tid & 7;
            bool rowok = (q0 + q) < nTok;
            float4 va = *(const float4*)&Ss[q][s * 8];
            float4 vb = *(const float4*)&Ss[q][s * 8 + 4];
            if (q0 == 0 && q == 0) {
                *(float4*)&s0row[jb + s * 8] = va;
                *(float4*)&s0row[jb + s * 8 + 4] = vb;
            }
            float mx = fmaxf(fmaxf(fmaxf(va.x, va.y), fmaxf(va.z, va.w)),
                             fmaxf(fmaxf(vb.x, vb.y), fmaxf(vb.z, vb.w)));
            #pragma unroll
            for (int o = 1; o < 8; o <<= 1) mx = fmaxf(mx, __shfl_xor(mx, o));
            float mold = mrow[q];
            float mnew = fmaxf(mold, mx);
            float e[8];
            float sum = 0.f;
            if (rowok) {
                e[0] = expf(va.x - mnew); e[1] = expf(va.y - mnew);
                e[2] = expf(va.z - mnew); e[3] = expf(va.w - mnew);
                e[4] = expf(vb.x - mnew); e[5] = expf(vb.y - mnew);
                e[6] = expf(vb.z - mnew); e[7] = expf(vb.w - mnew);
                sum = ((e[0] + e[1]) + (e[2] + e[3])) + ((e[4] + e[5]) + (e[6] + e[7]));
            } else {
                #pragma unroll
                for (int i = 0; i < 8; ++i) e[i] = 0.f;
            }
            #pragma unroll
            for (int o = 1; o < 8; o <<= 1) sum += __shfl_xor(sum, o);
            bf16x8 ph, pl;   // truncation split (e >= 0)
            #pragma unroll
            for (int i = 0; i < 8; ++i) {
                unsigned u = __builtin_bit_cast(unsigned, e[i]);
                ph[i] = (short)(u >> 16);
                float r = e[i] - __builtin_bit_cast(float, u & 0xffff0000u);
                pl[i] = (short)(__builtin_bit_cast(unsigned, r) >> 16);
            }
            int poff = q * 64 + ((s ^ (q & 7)) << 3);
            *(bf16x8*)&Ph[poff] = ph;
            *(bf16x8*)&Pl[poff] = pl;
            if (s == 0 && rowok) {
                float f = expf(mold - mnew);
                lrow[q] = lrow[q] * f + sum;
                mrow[q] = mnew;
                frow[q] = f;
            }
            if (q0 == 0 && tid < 64) {
                int jj = jb + tid;
                if (jj < nTok)
                    vnrow[jj] = sqrtf(vnpart[tid][0] + vnpart[tid][1]
                                    + vnpart[tid][2] + vnpart[tid][3]);
            }
        }
        __syncthreads();
        {   // PV: wave (qh, xh) computes 16q x 32d, accumulate
            float fe[4];
            #pragma unroll
            for (int e = 0; e < 4; ++e) fe[e] = frow[qh * 16 + fg * 4 + e];
            #pragma unroll
            for (int t = 0; t < 2; ++t)
                #pragma unroll
                for (int e = 0; e < 4; ++e) oacc[t][e] *= fe[e];
            #pragma unroll
            for (int s = 0; s < 2; ++s) {
                int pr = qh * 16 + fr;
                int poff = pr * 64 + (((s * 4 + fg) ^ (pr & 7)) << 3);
                bf16x8 pah = *(const bf16x8*)&Ph[poff];
                bf16x8 pal = *(const bf16x8*)&Pl[poff];
                #pragma unroll
                for (int t = 0; t < 2; ++t) {
                    int d = xh * 32 + t * 16 + fr;
                    int voff = d * 64 + (((s * 4 + fg) ^ (d & 7)) << 3);
                    bf16x8 vbh = *(const bf16x8*)&Vth[voff];
                    bf16x8 vbl = *(const bf16x8*)&Vtl[voff];
                    oacc[t] = __builtin_amdgcn_mfma_f32_16x16x32_bf16(pah, vbh, oacc[t], 0, 0, 0);
                    oacc[t] = __builtin_amdgcn_mfma_f32_16x16x32_bf16(pah, vbl, oacc[t], 0, 0, 0);
                    oacc[t] = __builtin_amdgcn_mfma_f32_16x16x32_bf16(pal, vbh, oacc[t], 0, 0, 0);
                }
            }
        }
    }
    // epilogue: O = acc / l -> swizzled planes (proj A format)
    #pragma unroll
    for (int e = 0; e < 4; ++e) {
        int qr = qh * 16 + fg * 4 + e;
        int q = q0 + qr;
        if (q < nTok) {
            float inv = 1.0f / lrow[qr];
            int m = b * NTOK + q;
            int xr = (m >> 1) & 3;
            #pragma unroll
            for (int t = 0; t < 2; ++t) {
                int n = h * 64 + xh * 32 + t * 16 + fr;
                unsigned short hh, ll;
                split2(oacc[t][e] * inv, hh, ll);
                size_t dst = (size_t)m * 768 + (n & ~31)
                           + ((((n >> 3) & 3) ^ xr) << 3) + (n & 7);
                oh_g[dst] = hh; ol_g[dst] = ll;
            }
        }
    }
    if (q0 == 0) {
        float m0f = mrow[0], l0 = lrow[0];
        for (int j = 1 + tid; j < nTok; j += 256)
            jacg[(size_t)bh * NPATCH + (j - 1)] = (expf(s0row[j] - m0f) / l0) * vnrow[j];
    }
}

// ------------------------------------------------------- prune decision
__global__ __launch_bounds__(256)
void decide_kernel(const float* __restrict__ jac,
                   int* __restrict__ nTokPtr, int* __restrict__ nTokNextPtr,
                   int* __restrict__ keepIdx, float* __restrict__ prevMassPtr,
                   int* __restrict__ prevValidPtr) {
    const int nTok = *nTokPtr;
    const int N = nTok - 1;
    const int tid = threadIdx.x;
    if (N <= 16) {
        if (tid == 0) { *prevValidPtr = 0; *nTokNextPtr = nTok; }
        for (int t = tid; t < nTok; t += 256) keepIdx[t] = t;
        return;
    }
    __shared__ float impF[NPATCH];
    __shared__ int   sel[NPATCH];
    __shared__ int   s_next;
    for (int j = tid; j < N; j += 256) {
        double s = 0.0;
        for (int r = 0; r < BB * NHEAD; r++) s += (double)jac[(size_t)r * NPATCH + j];
        impF[j] = (float)(s * (1.0 / 384.0));
    }
    __syncthreads();
    if (tid == 0) {
        double ms = 0.0;
        for (int j = 0; j < N; j++) ms += (double)impF[j];
        float massF = (float)ms;
        float meanF = (float)(ms / (double)N);
        double vs = 0.0;
        for (int j = 0; j < N; j++) { double d = (double)impF[j] - (double)meanF; vs += d * d; }
        float stdF = (float)sqrt(vs / (double)N);
        float rho = stdF / (meanF + 1e-6f);
        int nnext;
        if (*prevValidPtr != 0) {
            float pm = *prevMassPtr;
            float drift = fabsf(massF - pm) / (pm + 1e-6f);
            float kr = 1.0f - 0.01f * rho * (1.0f + drift);
            kr = fminf(fmaxf(kr, 0.0f), 1.0f);
            int t = (int)((double)N * (double)kr);
            nnext = t < 16 ? 16 : t;
        } else {
            nnext = N;
        }
        *prevMassPtr = massF;
        *prevValidPtr = 1;
        s_next = nnext;
        *nTokNextPtr = nnext + 1;
    }
    __syncthreads();
    int nnext = s_next;
    if (nnext < N) {
        for (int j = tid; j < N; j += 256) {
            float vj = impF[j];
            int rank = 0;
            for (int i = 0; i < N; i++) {
                float vi = impF[i];
                rank += (vi > vj || (vi == vj && i < j)) ? 1 : 0;
            }
            sel[j] = (rank < nnext) ? 1 : 0;
        }
        __syncthreads();
        if (tid == 0) {
            int c = 1;
            keepIdx[0] = 0;
            for (int j = 0; j < N; j++) if (sel[j]) keepIdx[c++] = j + 1;
        }
    } else {
        for (int t = tid; t < nTok; t += 256) keepIdx[t] = t;
    }
}

// ---------------------------------------------------------------- gather
__global__ __launch_bounds__(192)
void gather_kernel(const float* __restrict__ src, float* __restrict__ dst,
                   const int* __restrict__ keepIdx,
                   const int* __restrict__ nTokNextPtr, int* __restrict__ nTokPtr) {
    int nn = *nTokNextPtr;
    int m = blockIdx.x;
    int b = m / NTOK, t = m - b * NTOK;
    if (t < nn) {
        int s = keepIdx[t];
        const float4* sp = (const float4*)(src + ((size_t)b * NTOK + s) * DMODEL);
        float4* dp = (float4*)(dst + ((size_t)b * NTOK + t) * DMODEL);
        dp[threadIdx.x] = sp[threadIdx.x];
    }
    if (m == 0 && threadIdx.x == 0) *nTokPtr = nn;
}

// ---------------------------------------------------------------- head
__global__ __launch_bounds__(256)
void head_kernel(const float* __restrict__ lnC, const float* __restrict__ W,
                 const float* __restrict__ hb, float* __restrict__ out) {
    int b = blockIdx.x;
    int n = blockIdx.y * 256 + threadIdx.x;
    __shared__ float xs[DMODEL];
    for (int i = threadIdx.x; i < DMODEL; i += 256) xs[i] = lnC[(size_t)b * DMODEL + i];
    __syncthreads();
    if (n < NCLASS) {
        float acc = hb[n];
        for (int d = 0; d < DMODEL; d++) acc = fmaf(xs[d], W[(size_t)d * NCLASS + n], acc);
        out[(size_t)b * NCLASS + n] = acc;
    }
}

// ================================================================= launch
extern "C" void kernel_launch(void* const* d_in, const int* in_sizes, int n_in,
                              void* d_out, int out_size, void* d_ws, size_t ws_size,
                              hipStream_t stream) {
    const float* x       = (const float*)d_in[0];
    const float* patch_w = (const float*)d_in[1];
    const float* patch_b = (const float*)d_in[2];
    const float* cls_tok = (const float*)d_in[3];
    const float* pos     = (const float*)d_in[4];
    const float* ln1_w   = (const float*)d_in[5];
    const float* ln1_b   = (const float*)d_in[6];
    const float* qkv_w   = (const float*)d_in[7];
    const float* qkv_b   = (const float*)d_in[8];
    const float* proj_w  = (const float*)d_in[9];
    const float* proj_b  = (const float*)d_in[10];
    const float* ln2_w   = (const float*)d_in[11];
    const float* ln2_b   = (const float*)d_in[12];
    const float* fc1_w   = (const float*)d_in[13];
    const float* fc1_b   = (const float*)d_in[14];
    const float* fc2_w   = (const float*)d_in[15];
    const float* fc2_b   = (const float*)d_in[16];
    const float* norm_w  = (const float*)d_in[17];
    const float* norm_b  = (const float*)d_in[18];
    const float* head_w  = (const float*)d_in[19];
    const float* head_b  = (const float*)d_in[20];
    float* out = (float*)d_out;

    char* ws = (char*)d_ws;
    size_t off = 0;
    auto alloc = [&](size_t nbytes) {
        char* p = ws + off;
        off += ((nbytes + 255) / 256) * 256;
        return p;
    };
    float* tokA = (float*)alloc((size_t)MTOT * DMODEL * 4);
    float* tokB = (float*)alloc((size_t)MTOT * DMODEL * 4);
    // union: qkv planes (2 x MPAD x 2304 x 2B) | hb planes (2 x MPAD x 3072 x 2B)
    char* uni = alloc((size_t)2 * MPAD * 3072 * 2);
    unsigned short* qkvh = (unsigned short*)uni;
    unsigned short* qkvl = qkvh + (size_t)MPAD * 2304;
    unsigned short* hbh  = (unsigned short*)uni;
    unsigned short* hbl  = hbh + (size_t)MPAD * 3072;
    unsigned short* xnh  = (unsigned short*)alloc((size_t)MPAD * DMODEL * 2);
    unsigned short* xnl  = (unsigned short*)alloc((size_t)MPAD * DMODEL * 2);
    unsigned short* outh = (unsigned short*)alloc((size_t)MPAD * DMODEL * 2);
    unsigned short* outl = (unsigned short*)alloc((size_t)MPAD * DMODEL * 2);
    unsigned short* whi  = (unsigned short*)alloc(WTOTAL * 2);
    unsigned short* wlo  = (unsigned short*)alloc(WTOTAL * 2);
    unsigned short* wphi = (unsigned short*)alloc((size_t)768 * 768 * 2);
    unsigned short* wplo = (unsigned short*)alloc((size_t)768 * 768 * 2);
    float* jac  = (float*)alloc((size_t)BB * NHEAD * NPATCH * 4);
    float* lnC  = (float*)alloc((size_t)BB * DMODEL * 4);
    float* prevMass = (float*)alloc(32);
    int* ints = (int*)alloc(1024);
    int* nTokP = ints; int* nTokNextP = ints + 1; int* prevValidP = ints + 2;
    int* keepIdx = ints + 4;

    dim3 blk(256);
    state_init<<<dim3(1), dim3(1), 0, stream>>>(nTokP, prevValidP);
    wconv_patch<<<dim3(288), blk, 0, stream>>>(patch_w, wphi, wplo);
    cls_init<<<dim3(BB), blk, 0, stream>>>(cls_tok, pos, tokA);
    mfma_gemm<1, 3><<<dim3(49 * 6), blk, 0, stream>>>(
        nullptr, nullptr, x, wphi, wplo, patch_b, pos, tokA, nullptr,
        DMODEL, 768, BB * NPATCH, 49, 6, nTokP);

    float* bufs[2] = {tokA, tokB};
    const int gm = MPAD / 128;   // 50
    for (int l = 0; l < NLAYER; l++) {
        float* cur = bufs[l & 1];
        float* nxt = bufs[(l + 1) & 1];
        wconv_layer<<<dim3(6912), blk, 0, stream>>>(
            qkv_w + (size_t)l * 768 * 2304, proj_w + (size_t)l * 768 * 768,
            fc1_w + (size_t)l * 768 * 3072, fc2_w + (size_t)l * 3072 * 768, whi, wlo);
        ln_tok<<<dim3(MTOT), blk, 0, stream>>>(cur, xnh, xnl,
            ln1_w + l * 768, ln1_b + l * 768, nTokP);
        mfma_gemm<0, 0><<<dim3(gm * 18), blk, 0, stream>>>(
            xnh, xnl, nullptr, whi + WOFF_QKV, wlo + WOFF_QKV, qkv_b + (size_t)l * 2304,
            nullptr, qkvh, qkvl, 2304, 768, MTOT, gm, 18, nTokP);
        attn_v4<<<dim3(BB * NHEAD, 7), blk, 0, stream>>>(qkvh, qkvl, outh, outl, jac, nTokP);
        mfma_gemm<0, 1><<<dim3(gm * 6), blk, 0, stream>>>(
            outh, outl, nullptr, whi + WOFF_PROJ, wlo + WOFF_PROJ, proj_b + (size_t)l * 768,
            cur, cur, nullptr, 768, 768, MTOT, gm, 6, nTokP);
        ln_tok<<<dim3(MTOT), blk, 0, stream>>>(cur, xnh, xnl,
            ln2_w + l * 768, ln2_b + l * 768, nTokP);
        mfma_gemm<0, 2><<<dim3(gm * 24), blk, 0, stream>>>(
            xnh, xnl, nullptr, whi + WOFF_FC1, wlo + WOFF_FC1, fc1_b + (size_t)l * 3072,
            nullptr, hbh, hbl, 3072, 768, MTOT, gm, 24, nTokP);
        mfma_gemm<0, 1><<<dim3(gm * 6), blk, 0, stream>>>(
            hbh, hbl, nullptr, whi + WOFF_FC2, wlo + WOFF_FC2, fc2_b + (size_t)l * 768,
            cur, cur, nullptr, 768, 3072, MTOT, gm, 6, nTokP);
        decide_kernel<<<dim3(1), blk, 0, stream>>>(jac, nTokP, nTokNextP, keepIdx,
                                                   prevMass, prevValidP);
        gather_kernel<<<dim3(MTOT), dim3(192), 0, stream>>>(cur, nxt, keepIdx, nTokNextP, nTokP);
    }
    ln_cls<<<dim3(BB), blk, 0, stream>>>(bufs[0], lnC, norm_w, norm_b);
    head_kernel<<<dim3(BB, 4), blk, 0, stream>>>(lnC, head_w, head_b, out);
}